// Round 15
// baseline (74.646 us; speedup 1.0000x reference)
//
#include <hip/hip_runtime.h>
#include <math.h>

#define DIM   2048
#define NEXP  64
#define TOPK  8
#define BM    32
#define NT    512
#define NBLK  512          // M / BM
#define RSTRIDE 260        // padded LDS row slot, floats (1040 B, 16B-aligned)
#define BUF1  (32 * RSTRIDE)   // 8320 floats

typedef __attribute__((ext_vector_type(8)))  short bf16x8;
typedef __attribute__((ext_vector_type(16))) float f32x16;

#define MFMA(A, B, C) __builtin_amdgcn_mfma_f32_32x32x16_bf16(A, B, C, 0, 0, 0)
#define AS_BF(v) (*(const bf16x8*)&(v))

typedef __attribute__((address_space(3))) unsigned int       lds_uint;
typedef __attribute__((address_space(1))) const unsigned int glb_uint;

#define STR2(x) #x
#define STR(x) STR2(x)
#define GL16(dst, p, off) \
    asm volatile("global_load_dwordx4 %0, %1, off offset:" STR(off) \
                 : "=v"(dst) : "v"(p) : "memory")

__device__ inline unsigned int bfpack(float a, float b) {
    unsigned int ua = __float_as_uint(a), ub = __float_as_uint(b);
    unsigned int lo = (ua + 0x7FFFu + ((ua >> 16) & 1u)) >> 16;
    unsigned int hi = (ub + 0x7FFFu + ((ub >> 16) & 1u)) & 0xFFFF0000u;
    return hi | lo;
}
__device__ inline void split2pair(float a, float b, unsigned int& h, unsigned int& m) {
    h = bfpack(a, b);
    float ra = a - __uint_as_float(h << 16);
    float rb = b - __uint_as_float(h & 0xFFFF0000u);
    m = bfpack(ra, rb);
}

// w[e][k] f32 -> byte = (k/256)*65536 + ((k/16)&15)*4096 + (eh*2+term)*1024 + (kh*32+le)*16
__global__ __launch_bounds__(256) void prep_kernel(const float* __restrict__ w,
                                                   unsigned int* __restrict__ wpack) {
    const int u = blockIdx.x * 256 + threadIdx.x;   // 0..16383
    const int e = u >> 8, k8 = u & 255;
    const float4 v0 = *(const float4*)(w + (size_t)e * DIM + k8 * 8);
    const float4 v1 = *(const float4*)(w + (size_t)e * DIM + k8 * 8 + 4);
    unsigned int h[4], m[4];
    split2pair(v0.x, v0.y, h[0], m[0]);
    split2pair(v0.z, v0.w, h[1], m[1]);
    split2pair(v1.x, v1.y, h[2], m[2]);
    split2pair(v1.z, v1.w, h[3], m[3]);
    const int wv = k8 >> 5, t = (k8 >> 1) & 15, kh = k8 & 1;
    const int eh = e >> 5, le = e & 31;
    char* base = (char*)wpack + (size_t)wv * 65536 + t * 4096
               + (eh * 2) * 1024 + (kh * 32 + le) * 16;
    *(uint4*)(base)        = (uint4){h[0], h[1], h[2], h[3]};
    *(uint4*)(base + 1024) = (uint4){m[0], m[1], m[2], m[3]};
}

__global__ __launch_bounds__(NT, 4) void router_kernel(
    const float* __restrict__ x,
    const unsigned int* __restrict__ wpack,
    const float* __restrict__ bias,
    float* __restrict__ out,     // [M*8] scores | [M*8] idx(f32) | [64] counts(f32)
    int* __restrict__ histws,    // [NBLK][64]
    int M)
{
    // buffers: buf0 floats [0, 8320), buf1 [8320, 16640)  (66560 B): [32 rows][260 floats]
    // epilogue lg[8*32][66] (67584 B) aliases; hist after
    __shared__ __align__(16) char smem[67584 + 256];
    float* smemf = (float*)smem;
    int* hist = (int*)(smem + 67584);

    const int tid  = threadIdx.x;
    const int bid  = blockIdx.x;
    const int swz  = (bid & 7) * (NBLK / 8) + (bid >> 3);   // bijective XCD swizzle
    const int row0 = swz * BM;
    if (tid < NEXP) hist[tid] = 0;

    const int wv   = tid >> 6;      // wave id: stages rows 4wv..4wv+3; computes tiles 2wv,2wv+1
    const int lane = tid & 63;
    const int lr   = lane & 31;
    const int kh   = lane >> 5;

    // ---- x staging: each DMA reads ONE row's contiguous 1 KB, linear into padded slot ----
    const int xr0 = 4 * wv;
    const float* xsrc0 = x + (size_t)(row0 + xr0 + 0) * DIM + lane * 4;
    const float* xsrc1 = x + (size_t)(row0 + xr0 + 1) * DIM + lane * 4;
    const float* xsrc2 = x + (size_t)(row0 + xr0 + 2) * DIM + lane * 4;
    const float* xsrc3 = x + (size_t)(row0 + xr0 + 3) * DIM + lane * 4;
    const int xo0 = (xr0 + 0) * RSTRIDE, xo1 = (xr0 + 1) * RSTRIDE,
              xo2 = (xr0 + 2) * RSTRIDE, xo3 = (xr0 + 3) * RSTRIDE;

    // ---- w stream base: tile T = ph*16 + 2wv (+1) ----
    const char* wbase = (const char*)wpack + (2 * wv) * 4096 + lane * 16;

    // ---- compute read offsets (floats): row lr, k-local granule g (linear, no swizzle) ----
    const int g00 = 8 * wv + 2 * kh;        // tile 2wv
    const int a00 = lr * RSTRIDE + g00 * 4; // 8 floats: a00, a00+4
    const int a10 = a00 + 16;               // tile 2wv+1 (granules +4)

    f32x16 acc0 = {}, acc1 = {};
    uint4 w0h_A, w0m_A, w0H_A, w0M_A, w1h_A, w1m_A, w1H_A, w1M_A;
    uint4 w0h_B, w0m_B, w0H_B, w0M_B, w1h_B, w1m_B, w1H_B, w1M_B;

#define DMA4(BUFO, PH) do { \
        __builtin_amdgcn_global_load_lds((glb_uint*)(const void*)(xsrc0 + (PH) * 256), \
                                         (lds_uint*)(void*)(smemf + (BUFO) + xo0), 16, 0, 0); \
        __builtin_amdgcn_global_load_lds((glb_uint*)(const void*)(xsrc1 + (PH) * 256), \
                                         (lds_uint*)(void*)(smemf + (BUFO) + xo1), 16, 0, 0); \
        __builtin_amdgcn_global_load_lds((glb_uint*)(const void*)(xsrc2 + (PH) * 256), \
                                         (lds_uint*)(void*)(smemf + (BUFO) + xo2), 16, 0, 0); \
        __builtin_amdgcn_global_load_lds((glb_uint*)(const void*)(xsrc3 + (PH) * 256), \
                                         (lds_uint*)(void*)(smemf + (BUFO) + xo3), 16, 0, 0); \
        asm volatile("" ::: "memory"); \
    } while (0)

#define WLD(S, PH) do { \
        const char* a_ = wbase + (PH) * 65536; \
        const char* b_ = a_ + 4096; \
        GL16(w0h_##S, a_, 0);    GL16(w0m_##S, a_, 1024); \
        GL16(w0H_##S, a_, 2048); GL16(w0M_##S, a_, 3072); \
        GL16(w1h_##S, b_, 0);    GL16(w1m_##S, b_, 1024); \
        GL16(w1H_##S, b_, 2048); GL16(w1M_##S, b_, 3072); \
    } while (0)

#define DOSPLIT(vlo, vhi, hv, mv) do { \
        unsigned int h_[4], m_[4]; \
        split2pair((vlo).x, (vlo).y, h_[0], m_[0]); \
        split2pair((vlo).z, (vlo).w, h_[1], m_[1]); \
        split2pair((vhi).x, (vhi).y, h_[2], m_[2]); \
        split2pair((vhi).z, (vhi).w, h_[3], m_[3]); \
        hv = (uint4){h_[0], h_[1], h_[2], h_[3]}; \
        mv = (uint4){m_[0], m_[1], m_[2], m_[3]}; \
    } while (0)

#define COMPUTE(S, BUFO) do { \
        float4 alo0_ = *(const float4*)(smemf + (BUFO) + a00); \
        float4 ahi0_ = *(const float4*)(smemf + (BUFO) + a00 + 4); \
        float4 alo1_ = *(const float4*)(smemf + (BUFO) + a10); \
        float4 ahi1_ = *(const float4*)(smemf + (BUFO) + a10 + 4); \
        uint4 ah_, am_; \
        DOSPLIT(alo0_, ahi0_, ah_, am_); \
        acc0 = MFMA(AS_BF(ah_), AS_BF(w0h_##S), acc0); \
        acc0 = MFMA(AS_BF(am_), AS_BF(w0h_##S), acc0); \
        acc0 = MFMA(AS_BF(ah_), AS_BF(w0m_##S), acc0); \
        acc1 = MFMA(AS_BF(ah_), AS_BF(w0H_##S), acc1); \
        acc1 = MFMA(AS_BF(am_), AS_BF(w0H_##S), acc1); \
        acc1 = MFMA(AS_BF(ah_), AS_BF(w0M_##S), acc1); \
        DOSPLIT(alo1_, ahi1_, ah_, am_); \
        acc0 = MFMA(AS_BF(ah_), AS_BF(w1h_##S), acc0); \
        acc0 = MFMA(AS_BF(am_), AS_BF(w1h_##S), acc0); \
        acc0 = MFMA(AS_BF(ah_), AS_BF(w1m_##S), acc0); \
        acc1 = MFMA(AS_BF(ah_), AS_BF(w1H_##S), acc1); \
        acc1 = MFMA(AS_BF(am_), AS_BF(w1H_##S), acc1); \
        acc1 = MFMA(AS_BF(ah_), AS_BF(w1M_##S), acc1); \
    } while (0)

#define VMW(N) do { asm volatile("s_waitcnt vmcnt(" STR(N) ")" ::: "memory"); \
                    __builtin_amdgcn_sched_barrier(0); } while (0)
#define BAR __builtin_amdgcn_s_barrier()

    // prologue: phase-0 x into buf0, phase-0 w into slot A
    DMA4(0, 0); WLD(A, 0);
    VMW(8); BAR;                       // DMAs done (w A still in flight)
    // steady: issue next (DMA+W) -> vmcnt(12) frees current w -> compute -> vmcnt(8) -> barrier
    DMA4(BUF1, 1); WLD(B, 1); VMW(12); COMPUTE(A, 0);    VMW(8); BAR;   // ph0
    DMA4(0,    2); WLD(A, 2); VMW(12); COMPUTE(B, BUF1); VMW(8); BAR;   // ph1
    DMA4(BUF1, 3); WLD(B, 3); VMW(12); COMPUTE(A, 0);    VMW(8); BAR;   // ph2
    DMA4(0,    4); WLD(A, 4); VMW(12); COMPUTE(B, BUF1); VMW(8); BAR;   // ph3
    DMA4(BUF1, 5); WLD(B, 5); VMW(12); COMPUTE(A, 0);    VMW(8); BAR;   // ph4
    DMA4(0,    6); WLD(A, 6); VMW(12); COMPUTE(B, BUF1); VMW(8); BAR;   // ph5
    DMA4(BUF1, 7); WLD(B, 7); VMW(12); COMPUTE(A, 0);    VMW(8); BAR;   // ph6
    VMW(0); COMPUTE(B, BUF1);                                           // ph7

#undef VMW
#undef COMPUTE
#undef DOSPLIT
#undef WLD
#undef DMA4

    __syncthreads();

    // ---- split-K-8 partials into lg[8*32][66] (aliases buffers) ----
    float* lgf = smemf;
    #pragma unroll
    for (int r = 0; r < 16; ++r) {
        const int rr = (r & 3) + 8 * (r >> 2) + 4 * kh;   // verified C-layout (m74/m101)
        lgf[(wv * 32 + rr) * 66 + lr]      = acc0[r];
        lgf[(wv * 32 + rr) * 66 + 32 + lr] = acc1[r];
    }
    __syncthreads();

    // ---- top-k + softmax + histogram (verified epilogue); wave wv: 4 rows ----
    float* out_scores = out;
    float* out_idx    = out + (size_t)M * TOPK;

    #pragma unroll
    for (int i = 0; i < 4; ++i) {
        const int row = wv * 4 + i;
        float vm = bias[lane];
        #pragma unroll
        for (int p = 0; p < 8; ++p) vm += lgf[(p * 32 + row) * 66 + lane];

        float vals[TOPK];
        int   ids[TOPK];
        #pragma unroll
        for (int k = 0; k < TOPK; ++k) {
            float mv = vm;
            int   mi = lane;
            #pragma unroll
            for (int off = 32; off > 0; off >>= 1) {
                float ov = __shfl_xor(mv, off);
                int   oi = __shfl_xor(mi, off);
                if (ov > mv || (ov == mv && oi < mi)) { mv = ov; mi = oi; }
            }
            vals[k] = mv; ids[k] = mi;
            if (lane == mi) { vm = -INFINITY; atomicAdd(&hist[mi], 1); }
        }
        if (lane == 0) {
            const float m = vals[0];
            float e[TOPK];
            float ssum = 0.f;
            #pragma unroll
            for (int k = 0; k < TOPK; ++k) { e[k] = expf(vals[k] - m); ssum += e[k]; }
            const float inv = 1.0f / ssum;
            const size_t base = (size_t)(row0 + row) * TOPK;
            #pragma unroll
            for (int k = 0; k < TOPK; ++k) {
                out_scores[base + k] = e[k] * inv;
                out_idx[base + k]    = (float)ids[k];
            }
        }
    }

    __syncthreads();
    if (tid < NEXP) histws[bid * NEXP + tid] = hist[tid];
}

__global__ __launch_bounds__(512) void reduce_kernel(const int* __restrict__ histws,
                                                     float* __restrict__ counts) {
    __shared__ int partl[8][NEXP];
    const int t = threadIdx.x;
    const int e = t & 63, c = t >> 6;
    int sm = 0;
    for (int b = c; b < NBLK; b += 8) sm += histws[b * NEXP + e];
    partl[c][e] = sm;
    __syncthreads();
    if (t < NEXP) {
        int tot = 0;
        #pragma unroll
        for (int i = 0; i < 8; ++i) tot += partl[i][t];
        counts[t] = (float)tot;
    }
}

extern "C" void kernel_launch(void* const* d_in, const int* in_sizes, int n_in,
                              void* d_out, int out_size, void* d_ws, size_t ws_size,
                              hipStream_t stream) {
    const float* x    = (const float*)d_in[0];
    const float* w    = (const float*)d_in[1];
    const float* bias = (const float*)d_in[2];
    float* out = (float*)d_out;
    const int M = in_sizes[0] / DIM;   // 16384 rows

    unsigned int* wpack = (unsigned int*)d_ws;                      // 512 KB
    int* histws = (int*)((char*)d_ws + (1u << 20));                 // 128 KB
    float* out_counts = out + (size_t)2 * M * TOPK;

    prep_kernel<<<64, 256, 0, stream>>>(w, wpack);
    router_kernel<<<NBLK, NT, 0, stream>>>(x, wpack, bias, out, histws, M);
    reduce_kernel<<<1, 512, 0, stream>>>(histws, out_counts);
}

// Round 16
// 69.016 us; speedup vs baseline: 1.0816x; 1.0816x over previous
//
#include <hip/hip_runtime.h>
#include <math.h>

#define DIM   2048
#define NEXP  64
#define TOPK  8
#define BM    32
#define NT    512
#define NBLK  512          // M / BM
#define RSTRIDE 260        // padded LDS row slot, floats (1040 B, 16B-aligned)
#define BUF1  (32 * RSTRIDE)   // 8320 floats

typedef __attribute__((ext_vector_type(8)))  short bf16x8;
typedef __attribute__((ext_vector_type(16))) float f32x16;

#define MFMA(A, B, C) __builtin_amdgcn_mfma_f32_32x32x16_bf16(A, B, C, 0, 0, 0)
#define AS_BF(v) (*(const bf16x8*)&(v))

#define STR2(x) #x
#define STR(x) STR2(x)
#define GL16(dst, p, off) \
    asm volatile("global_load_dwordx4 %0, %1, off offset:" STR(off) \
                 : "=v"(dst) : "v"(p) : "memory")

__device__ inline unsigned int bfpack(float a, float b) {
    unsigned int ua = __float_as_uint(a), ub = __float_as_uint(b);
    unsigned int lo = (ua + 0x7FFFu + ((ua >> 16) & 1u)) >> 16;
    unsigned int hi = (ub + 0x7FFFu + ((ub >> 16) & 1u)) & 0xFFFF0000u;
    return hi | lo;
}
__device__ inline void split2pair(float a, float b, unsigned int& h, unsigned int& m) {
    h = bfpack(a, b);
    float ra = a - __uint_as_float(h << 16);
    float rb = b - __uint_as_float(h & 0xFFFF0000u);
    m = bfpack(ra, rb);
}

// w[e][k] f32 -> byte = (k/256)*65536 + ((k/16)&15)*4096 + (eh*2+term)*1024 + (kh*32+le)*16
__global__ __launch_bounds__(256) void prep_kernel(const float* __restrict__ w,
                                                   unsigned int* __restrict__ wpack) {
    const int u = blockIdx.x * 256 + threadIdx.x;   // 0..16383
    const int e = u >> 8, k8 = u & 255;
    const float4 v0 = *(const float4*)(w + (size_t)e * DIM + k8 * 8);
    const float4 v1 = *(const float4*)(w + (size_t)e * DIM + k8 * 8 + 4);
    unsigned int h[4], m[4];
    split2pair(v0.x, v0.y, h[0], m[0]);
    split2pair(v0.z, v0.w, h[1], m[1]);
    split2pair(v1.x, v1.y, h[2], m[2]);
    split2pair(v1.z, v1.w, h[3], m[3]);
    const int wv = k8 >> 5, t = (k8 >> 1) & 15, kh = k8 & 1;
    const int eh = e >> 5, le = e & 31;
    char* base = (char*)wpack + (size_t)wv * 65536 + t * 4096
               + (eh * 2) * 1024 + (kh * 32 + le) * 16;
    *(uint4*)(base)        = (uint4){h[0], h[1], h[2], h[3]};
    *(uint4*)(base + 1024) = (uint4){m[0], m[1], m[2], m[3]};
}

__global__ __launch_bounds__(NT, 4) void router_kernel(
    const float* __restrict__ x,
    const unsigned int* __restrict__ wpack,
    const float* __restrict__ bias,
    float* __restrict__ out,     // [M*8] scores | [M*8] idx(f32) | [64] counts(f32)
    int* __restrict__ histws,    // [NBLK][64]
    int M)
{
    // buf0 floats [0,8320), buf1 [8320,16640); lg[8*32][66] aliases; hist after
    __shared__ __align__(16) char smem[67584 + 256];
    float* smemf = (float*)smem;
    int* hist = (int*)(smem + 67584);

    const int tid  = threadIdx.x;
    const int bid  = blockIdx.x;
    const int swz  = (bid & 7) * (NBLK / 8) + (bid >> 3);   // bijective XCD swizzle
    const int row0 = swz * BM;
    if (tid < NEXP) hist[tid] = 0;

    const int wv   = tid >> 6;      // stages rows 4wv..4wv+3; computes tiles 2wv,2wv+1
    const int lane = tid & 63;
    const int lr   = lane & 31;
    const int kh   = lane >> 5;

    // ---- x: plain per-lane loads, 1 KB contiguous per GL16 (probe-style) ----
    const int xr0 = 4 * wv;
    const float* xsrc0 = x + (size_t)(row0 + xr0 + 0) * DIM + lane * 4;
    const float* xsrc1 = x + (size_t)(row0 + xr0 + 1) * DIM + lane * 4;
    const float* xsrc2 = x + (size_t)(row0 + xr0 + 2) * DIM + lane * 4;
    const float* xsrc3 = x + (size_t)(row0 + xr0 + 3) * DIM + lane * 4;
    const int xo0 = (xr0 + 0) * RSTRIDE + (lane << 2);
    const int xo1 = (xr0 + 1) * RSTRIDE + (lane << 2);
    const int xo2 = (xr0 + 2) * RSTRIDE + (lane << 2);
    const int xo3 = (xr0 + 3) * RSTRIDE + (lane << 2);

    // ---- w stream base: tile T = ph*16 + 2wv (+1) ----
    const char* wbase = (const char*)wpack + (2 * wv) * 4096 + lane * 16;

    // ---- compute read offsets (floats): linear (R15-verified) ----
    const int g00 = 8 * wv + 2 * kh;
    const int a00 = lr * RSTRIDE + g00 * 4;
    const int a10 = a00 + 16;

    f32x16 acc0 = {}, acc1 = {};
    uint4 xr0_, xr1_, xr2_, xr3_;
    uint4 w0h_, w0m_, w0H_, w0M_, w1h_, w1m_, w1H_, w1M_;

#define XLD(PH) do { \
        GL16(xr0_, xsrc0 + (PH) * 256, 0); \
        GL16(xr1_, xsrc1 + (PH) * 256, 0); \
        GL16(xr2_, xsrc2 + (PH) * 256, 0); \
        GL16(xr3_, xsrc3 + (PH) * 256, 0); \
    } while (0)

#define WLD(PH) do { \
        const char* a_ = wbase + (PH) * 65536; \
        const char* b_ = a_ + 4096; \
        GL16(w0h_, a_, 0);    GL16(w0m_, a_, 1024); \
        GL16(w0H_, a_, 2048); GL16(w0M_, a_, 3072); \
        GL16(w1h_, b_, 0);    GL16(w1m_, b_, 1024); \
        GL16(w1H_, b_, 2048); GL16(w1M_, b_, 3072); \
    } while (0)

#define DSW(BUFO) do { \
        *(uint4*)(smemf + (BUFO) + xo0) = xr0_; \
        *(uint4*)(smemf + (BUFO) + xo1) = xr1_; \
        *(uint4*)(smemf + (BUFO) + xo2) = xr2_; \
        *(uint4*)(smemf + (BUFO) + xo3) = xr3_; \
    } while (0)

#define DOSPLIT(vlo, vhi, hv, mv) do { \
        unsigned int h_[4], m_[4]; \
        split2pair((vlo).x, (vlo).y, h_[0], m_[0]); \
        split2pair((vlo).z, (vlo).w, h_[1], m_[1]); \
        split2pair((vhi).x, (vhi).y, h_[2], m_[2]); \
        split2pair((vhi).z, (vhi).w, h_[3], m_[3]); \
        hv = (uint4){h_[0], h_[1], h_[2], h_[3]}; \
        mv = (uint4){m_[0], m_[1], m_[2], m_[3]}; \
    } while (0)

#define COMPUTE(BUFO) do { \
        float4 alo0_ = *(const float4*)(smemf + (BUFO) + a00); \
        float4 ahi0_ = *(const float4*)(smemf + (BUFO) + a00 + 4); \
        float4 alo1_ = *(const float4*)(smemf + (BUFO) + a10); \
        float4 ahi1_ = *(const float4*)(smemf + (BUFO) + a10 + 4); \
        uint4 ah_, am_; \
        DOSPLIT(alo0_, ahi0_, ah_, am_); \
        acc0 = MFMA(AS_BF(ah_), AS_BF(w0h_), acc0); \
        acc0 = MFMA(AS_BF(am_), AS_BF(w0h_), acc0); \
        acc0 = MFMA(AS_BF(ah_), AS_BF(w0m_), acc0); \
        acc1 = MFMA(AS_BF(ah_), AS_BF(w0H_), acc1); \
        acc1 = MFMA(AS_BF(am_), AS_BF(w0H_), acc1); \
        acc1 = MFMA(AS_BF(ah_), AS_BF(w0M_), acc1); \
        DOSPLIT(alo1_, ahi1_, ah_, am_); \
        acc0 = MFMA(AS_BF(ah_), AS_BF(w1h_), acc0); \
        acc0 = MFMA(AS_BF(am_), AS_BF(w1h_), acc0); \
        acc0 = MFMA(AS_BF(ah_), AS_BF(w1m_), acc0); \
        acc1 = MFMA(AS_BF(ah_), AS_BF(w1H_), acc1); \
        acc1 = MFMA(AS_BF(am_), AS_BF(w1H_), acc1); \
        acc1 = MFMA(AS_BF(ah_), AS_BF(w1M_), acc1); \
    } while (0)

#define VMW(N) do { asm volatile("s_waitcnt vmcnt(" STR(N) ")" ::: "memory"); \
                    __builtin_amdgcn_sched_barrier(0); } while (0)
#define LGK0 asm volatile("s_waitcnt lgkmcnt(0)" ::: "memory")
#define BAR __builtin_amdgcn_s_barrier()

    // prologue: x(0)+w(0) in flight; x(0)->buf0
    XLD(0); WLD(0);
    VMW(8);            // x(0) regs ready (oldest 4); w(0) floats
    DSW(0); LGK0; BAR;

    // phase p: XLD(p+1) | VMW(4): w(p) ready | COMPUTE | WLD(p+1) | VMW(8): x(p+1) ready | DSW | BAR
    // p0
    XLD(1); VMW(4); COMPUTE(0);    WLD(1); VMW(8); DSW(BUF1); LGK0; BAR;
    // p1
    XLD(2); VMW(4); COMPUTE(BUF1); WLD(2); VMW(8); DSW(0);    LGK0; BAR;
    // p2
    XLD(3); VMW(4); COMPUTE(0);    WLD(3); VMW(8); DSW(BUF1); LGK0; BAR;
    // p3
    XLD(4); VMW(4); COMPUTE(BUF1); WLD(4); VMW(8); DSW(0);    LGK0; BAR;
    // p4
    XLD(5); VMW(4); COMPUTE(0);    WLD(5); VMW(8); DSW(BUF1); LGK0; BAR;
    // p5
    XLD(6); VMW(4); COMPUTE(BUF1); WLD(6); VMW(8); DSW(0);    LGK0; BAR;
    // p6
    XLD(7); VMW(4); COMPUTE(0);    WLD(7); VMW(8); DSW(BUF1); LGK0; BAR;
    // p7
    VMW(0); COMPUTE(BUF1);

#undef VMW
#undef LGK0
#undef COMPUTE
#undef DOSPLIT
#undef DSW
#undef WLD
#undef XLD

    __syncthreads();

    // ---- split-K-8 partials into lg[8*32][66] (aliases buffers) ----
    float* lgf = smemf;
    #pragma unroll
    for (int r = 0; r < 16; ++r) {
        const int rr = (r & 3) + 8 * (r >> 2) + 4 * kh;   // verified C-layout (m74/m101)
        lgf[(wv * 32 + rr) * 66 + lr]      = acc0[r];
        lgf[(wv * 32 + rr) * 66 + 32 + lr] = acc1[r];
    }
    __syncthreads();

    // ---- top-k + softmax + histogram (verified epilogue); wave wv: 4 rows ----
    float* out_scores = out;
    float* out_idx    = out + (size_t)M * TOPK;

    #pragma unroll
    for (int i = 0; i < 4; ++i) {
        const int row = wv * 4 + i;
        float vm = bias[lane];
        #pragma unroll
        for (int p = 0; p < 8; ++p) vm += lgf[(p * 32 + row) * 66 + lane];

        float vals[TOPK];
        int   ids[TOPK];
        #pragma unroll
        for (int k = 0; k < TOPK; ++k) {
            float mv = vm;
            int   mi = lane;
            #pragma unroll
            for (int off = 32; off > 0; off >>= 1) {
                float ov = __shfl_xor(mv, off);
                int   oi = __shfl_xor(mi, off);
                if (ov > mv || (ov == mv && oi < mi)) { mv = ov; mi = oi; }
            }
            vals[k] = mv; ids[k] = mi;
            if (lane == mi) { vm = -INFINITY; atomicAdd(&hist[mi], 1); }
        }
        if (lane == 0) {
            const float m = vals[0];
            float e[TOPK];
            float ssum = 0.f;
            #pragma unroll
            for (int k = 0; k < TOPK; ++k) { e[k] = expf(vals[k] - m); ssum += e[k]; }
            const float inv = 1.0f / ssum;
            const size_t base = (size_t)(row0 + row) * TOPK;
            #pragma unroll
            for (int k = 0; k < TOPK; ++k) {
                out_scores[base + k] = e[k] * inv;
                out_idx[base + k]    = (float)ids[k];
            }
        }
    }

    __syncthreads();
    if (tid < NEXP) histws[bid * NEXP + tid] = hist[tid];
}

__global__ __launch_bounds__(512) void reduce_kernel(const int* __restrict__ histws,
                                                     float* __restrict__ counts) {
    __shared__ int partl[8][NEXP];
    const int t = threadIdx.x;
    const int e = t & 63, c = t >> 6;
    int sm = 0;
    for (int b = c; b < NBLK; b += 8) sm += histws[b * NEXP + e];
    partl[c][e] = sm;
    __syncthreads();
    if (t < NEXP) {
        int tot = 0;
        #pragma unroll
        for (int i = 0; i < 8; ++i) tot += partl[i][t];
        counts[t] = (float)tot;
    }
}

extern "C" void kernel_launch(void* const* d_in, const int* in_sizes, int n_in,
                              void* d_out, int out_size, void* d_ws, size_t ws_size,
                              hipStream_t stream) {
    const float* x    = (const float*)d_in[0];
    const float* w    = (const float*)d_in[1];
    const float* bias = (const float*)d_in[2];
    float* out = (float*)d_out;
    const int M = in_sizes[0] / DIM;   // 16384 rows

    unsigned int* wpack = (unsigned int*)d_ws;                      // 512 KB
    int* histws = (int*)((char*)d_ws + (1u << 20));                 // 128 KB
    float* out_counts = out + (size_t)2 * M * TOPK;

    prep_kernel<<<64, 256, 0, stream>>>(w, wpack);
    router_kernel<<<NBLK, NT, 0, stream>>>(x, wpack, bias, out, histws, M);
    reduce_kernel<<<1, 512, 0, stream>>>(histws, out_counts);
}